// Round 2
// baseline (262.687 us; speedup 1.0000x reference)
//
#include <hip/hip_runtime.h>
#include <hip/hip_cooperative_groups.h>
#include <stdint.h>

namespace cg = cooperative_groups;

#define NDIM  256   // accumulator width
#define NFEAT 640   // piece features per sample
#define NROWS 641   // 640 features + 1 king bias row
#define SG    8     // slots processed together per unit
#define KCAP  2048  // per-king slot-list capacity (= MAXSLOTS, covers any skew)
#define MAXSLOTS 2048
#define GRID_MAIN 1024
#define OFF_KCNT  8                      // ws int offsets
#define OFF_KLIST 128
#define OFF_PART  (OFF_KLIST + 64 * KCAP)   // 131200 ints

typedef unsigned short ushort4v __attribute__((ext_vector_type(4)));

// LDS overlay for the fused kernel's three phases (phases separated by grid.sync)
struct FusedLds {
    union {
        unsigned mask[4][320];   // gather: per-WAVE row-activity masks (5120 B) -> no barriers
        struct { alignas(16) int8_t x[NDIM]; int fc[256]; alignas(4) int8_t x2[32]; } c;
        int bcnt;                // bucket: per-king LDS compaction counter
    };
};

__device__ __forceinline__ void detect_flags(const void* W, const void* pp,
                                             int* raww, int* rawpp)
{
    int a = 0, b = 0;
    const int* W32 = (const int*)W;
    const int* pp32 = (const int*)pp;
    for (int i = 0; i < 16; ++i) {
        const int v = W32[i];                  // int32 layout => |v| <= 32767
        if (v > 32767 || v < -32768) a = 1;    // packed int16 pairs look huge
        const int u = pp32[i];                 // int32 layout => {0,1}
        if (u != 0 && u != 1) b = 1;           // packed bool bytes exceed 1
    }
    *raww = a; *rawpp = b;
}

// ============================ phase 0: distributed bucketing ============================
// Block k (k < 64) compacts king k's slot ids into klist[k*KCAP..] (unordered — u16 adds
// commute so group composition/order is irrelevant). ~8 coalesced sweeps + LDS atomics.
__device__ __forceinline__ void bucket_phase(const int* __restrict__ kp, int nslots,
                                             int* __restrict__ kcnt, int* __restrict__ klist,
                                             int* __restrict__ bcnt)
{
    const int bid = blockIdx.x, t = threadIdx.x;
    if (bid >= 64) return;
    if (t == 0) *bcnt = 0;
    __syncthreads();
    for (int s = t; s < nslots; s += 256) {
        if (kp[s] == bid) {
            const int pos = atomicAdd(bcnt, 1);
            if (pos < KCAP) klist[bid * KCAP + pos] = s;
        }
    }
    __syncthreads();
    if (t == 0) kcnt[bid] = (*bcnt > KCAP) ? KCAP : *bcnt;
}

// ============================ phase 1: wave-autonomous gather ============================
// Unit = (king k, row-part p, slot-group gi). Each WAVE owns whole units: builds its own
// row masks in a private LDS strip, accumulates packed-u16 partials in registers (lane l
// holds dims [4l,4l+4)), stores directly to partial[p][slot]. Zero __syncthreads.
template<bool RAWW, bool RAWPP>
__device__ __forceinline__ void gather_phase(
    const void* __restrict__ ppv, const void* __restrict__ Wv,
    const int* __restrict__ kcnt, const int* __restrict__ klist,
    unsigned short* __restrict__ partial, int nslots, int rp,
    unsigned* __restrict__ maskbase)
{
    const int bid = blockIdx.x;
    const int k = bid & 63;                    // bid%8 == k%8 -> XCD pinning for W[k]
    const int t = threadIdx.x, l = t & 63, g = t >> 6;
    const int nwv = (gridDim.x >> 6) << 2;     // waves per king (64 at grid 1024)
    const int wv0 = ((bid >> 6) << 2) + g;
    unsigned* mym = maskbase + g * 320;        // this wave's private mask strip

    const int cnt = kcnt[k];
    if (cnt <= 0) return;
    const int gmax = (cnt + SG - 1) >> 3;
    const int nunits = rp * gmax;              // covers ANY cnt <= KCAP
    const int rpb = NFEAT / rp;                // 160 (rp=4) or 320 (rp=2)
    const int pshift = (rp == 4) ? 2 : 1;
    const char* Wk = (const char*)Wv + (size_t)k * NROWS * NDIM * (RAWW ? 2 : 4);
    const int* kl = klist + k * KCAP;

    for (int u = wv0; u < nunits; u += nwv) {
        const int p = u & (rp - 1);
        const int gi = u >> pshift;
        const int base = gi * SG;
        const int ns = min(SG, cnt - base);
        const int r0 = p * rpb;

        int slots[SG], samps[SG];
        #pragma unroll
        for (int i = 0; i < SG; ++i) {
            const int s = kl[base + (i < ns ? i : ns - 1)];
            slots[i] = s; samps[i] = s >> 1;   // s = 2*sample + side
        }

        // per-wave mask build: lane handles rows r = l, l+64, ...
        for (int r = l; r < rpb; r += 64) {
            unsigned mm = 0;
            #pragma unroll
            for (int i = 0; i < SG; ++i) {
                int v;
                if (RAWPP) v = ((const uint8_t*)ppv)[(size_t)samps[i] * NFEAT + r0 + r];
                else       v = ((const int*)ppv)[(size_t)samps[i] * NFEAT + r0 + r];
                mm |= (v != 0 ? 1u : 0u) << i;
            }
            mym[r] = (ns < SG) ? (mm & ((1u << ns) - 1u)) : mm;
        }
        // wave-local LDS visibility (private strip -> only this wave's writes matter)
        asm volatile("s_waitcnt lgkmcnt(0)" ::: "memory");

        ushort4v acc[SG];
        #pragma unroll
        for (int i = 0; i < SG; ++i) acc[i] = (ushort4v)0;

        // row loop: 4 row loads in flight, scalar-branch masked packed-u16 adds (mod 2^16)
        const char* rb = Wk + (size_t)r0 * (RAWW ? 512 : 1024) + (size_t)l * (RAWW ? 8 : 16);
        const int rstep = RAWW ? 2048 : 4096;
        for (int r = 0; r < rpb; r += 4, rb += rstep) {
            ushort4v w0, w1, w2, w3;
            if constexpr (RAWW) {
                w0 = *(const ushort4v*)(rb);
                w1 = *(const ushort4v*)(rb + 512);
                w2 = *(const ushort4v*)(rb + 1024);
                w3 = *(const ushort4v*)(rb + 1536);
            } else {
                const int4 u0 = *(const int4*)(rb);
                const int4 u1 = *(const int4*)(rb + 1024);
                const int4 u2 = *(const int4*)(rb + 2048);
                const int4 u3 = *(const int4*)(rb + 3072);
                w0.x=(unsigned short)u0.x; w0.y=(unsigned short)u0.y; w0.z=(unsigned short)u0.z; w0.w=(unsigned short)u0.w;
                w1.x=(unsigned short)u1.x; w1.y=(unsigned short)u1.y; w1.z=(unsigned short)u1.z; w1.w=(unsigned short)u1.w;
                w2.x=(unsigned short)u2.x; w2.y=(unsigned short)u2.y; w2.z=(unsigned short)u2.z; w2.w=(unsigned short)u2.w;
                w3.x=(unsigned short)u3.x; w3.y=(unsigned short)u3.y; w3.z=(unsigned short)u3.z; w3.w=(unsigned short)u3.w;
            }
            unsigned m0 = mym[r+0], m1 = mym[r+1], m2 = mym[r+2], m3 = mym[r+3];
            m0 = __builtin_amdgcn_readfirstlane(m0);   // wave-uniform -> scalar branches
            m1 = __builtin_amdgcn_readfirstlane(m1);
            m2 = __builtin_amdgcn_readfirstlane(m2);
            m3 = __builtin_amdgcn_readfirstlane(m3);
            #pragma unroll
            for (int i = 0; i < SG; ++i) {
                if (m0 & (1u << i)) acc[i] += w0;      // 2x v_pk_add_u16 each
                if (m1 & (1u << i)) acc[i] += w1;
                if (m2 & (1u << i)) acc[i] += w2;
                if (m3 & (1u << i)) acc[i] += w3;
            }
        }

        // direct store: lane l writes dims [4l,4l+4) -> 512 B/wave coalesced
        #pragma unroll
        for (int i = 0; i < SG; ++i)
            if (i < ns)
                *(ushort4v*)&partial[((size_t)p * nslots + slots[i]) * NDIM + (size_t)l * 4] = acc[i];
    }
}

// ============================ phase 2: combine + FC + ticket finalize ============================
template<bool RAWW>
__device__ __forceinline__ void combine_phase(
    const unsigned short* __restrict__ partial, const int* __restrict__ kp,
    const void* __restrict__ Wv, const void* __restrict__ ibv,
    const void* __restrict__ w1v, const int* __restrict__ b1,
    const void* __restrict__ w2v, const int* __restrict__ b2,
    const void* __restrict__ owv, const int* __restrict__ ob,
    int* __restrict__ ws, int* __restrict__ out,
    int nslots, int B, int rp, FusedLds& sh)
{
    const int t = threadIdx.x;
    int blocksum = 0;

    for (int b = blockIdx.x; b < B; b += gridDim.x) {
        const int k0 = kp[2 * b + 0];
        const int k1 = kp[2 * b + 1];
        {
            unsigned tot = 0;  // u16 arithmetic carried in u32; truncate at end
            for (int pi = 0; pi < rp; ++pi) {
                tot += partial[((size_t)pi * nslots + 2 * b + 0) * NDIM + t];
                tot += partial[((size_t)pi * nslots + 2 * b + 1) * NDIM + t];
            }
            if (RAWW) {
                const uint16_t* Wq = (const uint16_t*)Wv;
                tot += Wq[((size_t)k0 * NROWS + NFEAT) * NDIM + t];
                tot += Wq[((size_t)k1 * NROWS + NFEAT) * NDIM + t];
                tot += ((const uint16_t*)ibv)[t];
            } else {
                const int* Wq = (const int*)Wv;
                tot += (unsigned)Wq[((size_t)k0 * NROWS + NFEAT) * NDIM + t];
                tot += (unsigned)Wq[((size_t)k1 * NROWS + NFEAT) * NDIM + t];
                tot += (unsigned)((const int*)ibv)[t];
            }
            int v = (int)(int16_t)(uint16_t)tot;   // int16 wraparound semantics
            v = v < 0 ? 0 : (v > 127 ? 127 : v);
            sh.c.x[t] = (int8_t)v;
        }
        __syncthreads();

        // ---- FC1: 32 outputs over concat([x,x]) = fold the two 256-halves of w1 ----
        {
            const int o = t >> 3, part = t & 7;
            int y = 0;
            const uint32_t* xw = (const uint32_t*)sh.c.x;
            if (RAWW) {
                const uint32_t* w1r = (const uint32_t*)((const char*)w1v + o * 512);
                #pragma unroll
                for (int i = 0; i < 8; ++i) {
                    const int wi = part * 8 + i;
                    const uint32_t xv = xw[wi];
                    const uint32_t wa = w1r[wi];
                    const uint32_t wb = w1r[64 + wi];
                    #pragma unroll
                    for (int jj = 0; jj < 4; ++jj) {
                        const int xj  = (int)((xv >> (8 * jj)) & 0xFFu);
                        const int waj = (int)(int8_t)(uint8_t)(wa >> (8 * jj));
                        const int wbj = (int)(int8_t)(uint8_t)(wb >> (8 * jj));
                        y += xj * (waj + wbj);
                    }
                }
            } else {
                const int* w1r = (const int*)w1v + o * 512;
                #pragma unroll
                for (int i = 0; i < 8; ++i) {
                    const int wi = part * 8 + i;
                    const uint32_t xv = xw[wi];
                    #pragma unroll
                    for (int jj = 0; jj < 4; ++jj) {
                        const int xj = (int)((xv >> (8 * jj)) & 0xFFu);
                        y += xj * (w1r[wi * 4 + jj] + w1r[256 + wi * 4 + jj]);
                    }
                }
            }
            sh.c.fc[t] = y;
        }
        __syncthreads();

        if (t < 32) {
            int y = b1[t];
            #pragma unroll
            for (int pq = 0; pq < 8; ++pq) y += sh.c.fc[t * 8 + pq];
            y >>= 6;                                  // floor_divide(y, 64)
            y = y < 0 ? 0 : (y > 127 ? 127 : y);
            sh.c.x2[t] = (int8_t)y;
        }
        __syncthreads();

        // ---- FC2 + output dot ----
        if (t < 32) {
            int y = b2[t];
            const uint32_t* x2w = (const uint32_t*)sh.c.x2;
            if (RAWW) {
                const uint32_t* w2r = (const uint32_t*)((const char*)w2v + t * 32);
                #pragma unroll
                for (int i = 0; i < 8; ++i) {
                    const uint32_t xv = x2w[i];
                    const uint32_t wv = w2r[i];
                    #pragma unroll
                    for (int jj = 0; jj < 4; ++jj)
                        y += (int)((xv >> (8 * jj)) & 0xFFu) * (int)(int8_t)(uint8_t)(wv >> (8 * jj));
                }
            } else {
                const int* w2r = (const int*)w2v + t * 32;
                #pragma unroll
                for (int i = 0; i < 8; ++i) {
                    const uint32_t xv = x2w[i];
                    #pragma unroll
                    for (int jj = 0; jj < 4; ++jj)
                        y += (int)((xv >> (8 * jj)) & 0xFFu) * w2r[i * 4 + jj];
                }
            }
            y >>= 6;
            y = y < 0 ? 0 : (y > 127 ? 127 : y);
            const int owx = RAWW ? (int)((const int8_t*)owv)[t] : ((const int*)owv)[t];
            int pr = y * owx;
            #pragma unroll
            for (int off = 16; off > 0; off >>= 1) pr += __shfl_down(pr, off, 32);
            if (t == 0) blocksum += pr;
        }
        __syncthreads();   // sh.c reused next sample
    }

    // one atomic per participating block; last ticket writes the output
    const int nticket = (int)gridDim.x < B ? (int)gridDim.x : B;
    if (t == 0 && (int)blockIdx.x < nticket) {
        atomicAdd(&ws[0], blocksum);
        __threadfence();                               // order add before ticket (device scope)
        const int ticket = atomicAdd(&ws[3], 1);
        if (ticket == nticket - 1) {
            const int s = atomicAdd(&ws[0], 0);        // device-scope read
            out[0] = (s + ob[0]) >> 4;                 // floor_divide(s, 16)
        }
    }
}

// ============================ fused cooperative kernel ============================
__global__ __launch_bounds__(256, 4) void nnue_fused(
    const void* __restrict__ pp, const int* __restrict__ kp,
    const void* __restrict__ W,  const void* __restrict__ ib,
    const void* __restrict__ w1, const int* __restrict__ b1,
    const void* __restrict__ w2, const int* __restrict__ b2,
    const void* __restrict__ ow, const int* __restrict__ ob,
    int* __restrict__ ws, int* __restrict__ out,
    int nslots, int B, int rp)
{
    __shared__ FusedLds sh;
    __shared__ int s_raww, s_rawpp;
    const int t = threadIdx.x;
    if (t == 0) {
        detect_flags(W, pp, &s_raww, &s_rawpp);
        if (blockIdx.x == 0) { ws[0] = 0; ws[3] = 0; }
    }
    __syncthreads();
    const int raww = s_raww, rawpp = s_rawpp;

    int* kcnt  = ws + OFF_KCNT;
    int* klist = ws + OFF_KLIST;
    unsigned short* partial = (unsigned short*)(ws + OFF_PART);

    bucket_phase(kp, nslots, kcnt, klist, &sh.bcnt);
    cg::this_grid().sync();

    if (raww) {
        if (rawpp) gather_phase<true,  true >(pp, W, kcnt, klist, partial, nslots, rp, &sh.mask[0][0]);
        else       gather_phase<true,  false>(pp, W, kcnt, klist, partial, nslots, rp, &sh.mask[0][0]);
    } else {
        if (rawpp) gather_phase<false, true >(pp, W, kcnt, klist, partial, nslots, rp, &sh.mask[0][0]);
        else       gather_phase<false, false>(pp, W, kcnt, klist, partial, nslots, rp, &sh.mask[0][0]);
    }
    cg::this_grid().sync();

    if (raww) combine_phase<true >(partial, kp, W, ib, w1, b1, w2, b2, ow, ob, ws, out, nslots, B, rp, sh);
    else      combine_phase<false>(partial, kp, W, ib, w1, b1, w2, b2, ow, ob, ws, out, nslots, B, rp, sh);
}

// ============================ non-cooperative fallback kernels ============================
__global__ __launch_bounds__(256) void k_bucket(const int* __restrict__ kp,
                                                int* __restrict__ ws, int nslots)
{
    __shared__ int bcnt;
    if (blockIdx.x == 0 && threadIdx.x == 0) { ws[0] = 0; ws[3] = 0; }
    bucket_phase(kp, nslots, ws + OFF_KCNT, ws + OFF_KLIST, &bcnt);
}

__global__ __launch_bounds__(256, 4) void k_gather(
    const void* __restrict__ pp, const void* __restrict__ W,
    int* __restrict__ ws, int nslots, int rp)
{
    __shared__ FusedLds sh;
    __shared__ int s_raww, s_rawpp;
    if (threadIdx.x == 0) detect_flags(W, pp, &s_raww, &s_rawpp);
    __syncthreads();
    const int raww = s_raww, rawpp = s_rawpp;
    int* kcnt  = ws + OFF_KCNT;
    int* klist = ws + OFF_KLIST;
    unsigned short* partial = (unsigned short*)(ws + OFF_PART);
    if (raww) {
        if (rawpp) gather_phase<true,  true >(pp, W, kcnt, klist, partial, nslots, rp, &sh.mask[0][0]);
        else       gather_phase<true,  false>(pp, W, kcnt, klist, partial, nslots, rp, &sh.mask[0][0]);
    } else {
        if (rawpp) gather_phase<false, true >(pp, W, kcnt, klist, partial, nslots, rp, &sh.mask[0][0]);
        else       gather_phase<false, false>(pp, W, kcnt, klist, partial, nslots, rp, &sh.mask[0][0]);
    }
}

__global__ __launch_bounds__(256) void k_combine(
    const int* __restrict__ kp, const void* __restrict__ pp, const void* __restrict__ W,
    const void* __restrict__ ib,
    const void* __restrict__ w1, const int* __restrict__ b1,
    const void* __restrict__ w2, const int* __restrict__ b2,
    const void* __restrict__ ow, const int* __restrict__ ob,
    int* __restrict__ ws, int* __restrict__ out, int nslots, int B, int rp)
{
    __shared__ FusedLds sh;
    __shared__ int s_raww, s_rawpp;
    if (threadIdx.x == 0) detect_flags(W, pp, &s_raww, &s_rawpp);
    __syncthreads();
    unsigned short* partial = (unsigned short*)(ws + OFF_PART);
    if (s_raww) combine_phase<true >(partial, kp, W, ib, w1, b1, w2, b2, ow, ob, ws, out, nslots, B, rp, sh);
    else        combine_phase<false>(partial, kp, W, ib, w1, b1, w2, b2, ow, ob, ws, out, nslots, B, rp, sh);
}

// ============================ mono fallback (tiny ws / huge batch) ============================
struct SharedBuf {
    uint8_t pp[NFEAT];
    int     acc[4][NDIM];
    alignas(16) int8_t x[NDIM];
    int     fc[256];
    alignas(4) int8_t x2[32];
    int     list[4][160];
};

__global__ void detect_layout(const int* __restrict__ W32, const int* __restrict__ pp32,
                              int* __restrict__ ws) {
    int raww, rawpp;
    detect_flags(W32, pp32, &raww, &rawpp);
    ws[0] = 0; ws[1] = raww; ws[2] = rawpp;
}

template<bool RAWW, bool RAWPP>
__device__ __forceinline__ void mono_body(
    const void* __restrict__ ppv, const int* __restrict__ kp,
    const void* __restrict__ Wv,  const void* __restrict__ ibv,
    const void* __restrict__ w1v, const int* __restrict__ b1,
    const void* __restrict__ w2v, const int* __restrict__ b2,
    const void* __restrict__ owv, int* __restrict__ ws, SharedBuf& sh)
{
    const int b = blockIdx.x;
    const int t = threadIdx.x;
    const int l = t & 63;
    const int g = t >> 6;

    if (RAWPP) {
        const uint32_t* src = (const uint32_t*)((const uint8_t*)ppv + (size_t)b * NFEAT);
        if (t < NFEAT / 4) ((uint32_t*)sh.pp)[t] = src[t];
    } else {
        const int* src = (const int*)ppv + (size_t)b * NFEAT;
        for (int i = t; i < NFEAT; i += 256) sh.pp[i] = (uint8_t)(src[i] != 0);
    }
    __syncthreads();

    const int base = g * 160;
    int cnt = 0;
    for (int c = 0; c < 160; c += 64) {
        const int idx = c + l;
        const bool flag = (idx < 160) && (sh.pp[base + idx] != 0);
        const unsigned long long mmask = __ballot(flag);
        const int pos = cnt + (int)__popcll(mmask & ((1ull << l) - 1ull));
        if (flag) sh.list[g][pos] = base + idx;
        cnt += (int)__popcll(mmask);
    }

    const int k0 = kp[b * 2 + 0];
    const int k1 = kp[b * 2 + 1];
    int a0 = 0, a1 = 0, a2 = 0, a3 = 0, a4 = 0, a5 = 0, a6 = 0, a7 = 0;

    if (RAWW) {
        const char* W0 = (const char*)Wv + (size_t)k0 * (NROWS * NDIM * 2);
        const char* W1 = (const char*)Wv + (size_t)k1 * (NROWS * NDIM * 2);
        const int lo = l * 8;
        auto step = [&](int f) {
            const uint2 u0 = *(const uint2*)(W0 + f * 512 + lo);
            const uint2 u1 = *(const uint2*)(W1 + f * 512 + lo);
            a0 += (int)(u0.x & 0xFFFFu); a1 += (int)(u0.x >> 16);
            a2 += (int)(u0.y & 0xFFFFu); a3 += (int)(u0.y >> 16);
            a4 += (int)(u1.x & 0xFFFFu); a5 += (int)(u1.x >> 16);
            a6 += (int)(u1.y & 0xFFFFu); a7 += (int)(u1.y >> 16);
        };
        int j = 0;
        for (; j + 4 <= cnt; j += 4) {
            const int f0 = sh.list[g][j], f1 = sh.list[g][j + 1];
            const int f2 = sh.list[g][j + 2], f3 = sh.list[g][j + 3];
            step(f0); step(f1); step(f2); step(f3);
        }
        for (; j < cnt; ++j) step(sh.list[g][j]);
    } else {
        const char* W0 = (const char*)Wv + (size_t)k0 * (NROWS * NDIM * 4);
        const char* W1 = (const char*)Wv + (size_t)k1 * (NROWS * NDIM * 4);
        const int lo = l * 16;
        auto step = [&](int f) {
            const int4 u0 = *(const int4*)(W0 + f * 1024 + lo);
            const int4 u1 = *(const int4*)(W1 + f * 1024 + lo);
            a0 += u0.x; a1 += u0.y; a2 += u0.z; a3 += u0.w;
            a4 += u1.x; a5 += u1.y; a6 += u1.z; a7 += u1.w;
        };
        int j = 0;
        for (; j + 4 <= cnt; j += 4) {
            const int f0 = sh.list[g][j], f1 = sh.list[g][j + 1];
            const int f2 = sh.list[g][j + 2], f3 = sh.list[g][j + 3];
            step(f0); step(f1); step(f2); step(f3);
        }
        for (; j < cnt; ++j) step(sh.list[g][j]);
    }

    sh.acc[g][4 * l + 0] = a0 + a4;
    sh.acc[g][4 * l + 1] = a1 + a5;
    sh.acc[g][4 * l + 2] = a2 + a6;
    sh.acc[g][4 * l + 3] = a3 + a7;
    __syncthreads();

    {
        const int d = t;
        int tot = sh.acc[0][d] + sh.acc[1][d] + sh.acc[2][d] + sh.acc[3][d];
        int kb0, kb1, ibx;
        if (RAWW) {
            const int16_t* Wq = (const int16_t*)Wv;
            kb0 = Wq[((size_t)k0 * NROWS + NFEAT) * NDIM + d];
            kb1 = Wq[((size_t)k1 * NROWS + NFEAT) * NDIM + d];
            ibx = ((const int16_t*)ibv)[d];
        } else {
            const int* Wq = (const int*)Wv;
            kb0 = Wq[((size_t)k0 * NROWS + NFEAT) * NDIM + d];
            kb1 = Wq[((size_t)k1 * NROWS + NFEAT) * NDIM + d];
            ibx = ((const int*)ibv)[d];
        }
        tot += kb0 + kb1 + ibx;
        int v = (int)(int16_t)(uint16_t)(uint32_t)tot;
        v = v < 0 ? 0 : (v > 127 ? 127 : v);
        sh.x[d] = (int8_t)v;
    }
    __syncthreads();

    {
        const int o = t >> 3, part = t & 7;
        int y = 0;
        const uint32_t* xw = (const uint32_t*)sh.x;
        if (RAWW) {
            const uint32_t* w1r = (const uint32_t*)((const char*)w1v + o * 512);
            #pragma unroll
            for (int i = 0; i < 8; ++i) {
                const int wi = part * 8 + i;
                const uint32_t xv = xw[wi];
                const uint32_t wa = w1r[wi];
                const uint32_t wb = w1r[64 + wi];
                #pragma unroll
                for (int jj = 0; jj < 4; ++jj) {
                    const int xj  = (int)((xv >> (8 * jj)) & 0xFFu);
                    const int waj = (int)(int8_t)(uint8_t)(wa >> (8 * jj));
                    const int wbj = (int)(int8_t)(uint8_t)(wb >> (8 * jj));
                    y += xj * (waj + wbj);
                }
            }
        } else {
            const int* w1r = (const int*)w1v + o * 512;
            #pragma unroll
            for (int i = 0; i < 8; ++i) {
                const int wi = part * 8 + i;
                const uint32_t xv = xw[wi];
                #pragma unroll
                for (int jj = 0; jj < 4; ++jj) {
                    const int xj = (int)((xv >> (8 * jj)) & 0xFFu);
                    y += xj * (w1r[wi * 4 + jj] + w1r[256 + wi * 4 + jj]);
                }
            }
        }
        sh.fc[t] = y;
    }
    __syncthreads();

    if (t < 32) {
        int y = b1[t];
        #pragma unroll
        for (int pq = 0; pq < 8; ++pq) y += sh.fc[t * 8 + pq];
        y >>= 6;
        y = y < 0 ? 0 : (y > 127 ? 127 : y);
        sh.x2[t] = (int8_t)y;
    }
    __syncthreads();

    if (t < 32) {
        int y = b2[t];
        const uint32_t* x2w = (const uint32_t*)sh.x2;
        if (RAWW) {
            const uint32_t* w2r = (const uint32_t*)((const char*)w2v + t * 32);
            #pragma unroll
            for (int i = 0; i < 8; ++i) {
                const uint32_t xv = x2w[i];
                const uint32_t wv = w2r[i];
                #pragma unroll
                for (int jj = 0; jj < 4; ++jj)
                    y += (int)((xv >> (8 * jj)) & 0xFFu) * (int)(int8_t)(uint8_t)(wv >> (8 * jj));
            }
        } else {
            const int* w2r = (const int*)w2v + t * 32;
            #pragma unroll
            for (int i = 0; i < 8; ++i) {
                const uint32_t xv = x2w[i];
                #pragma unroll
                for (int jj = 0; jj < 4; ++jj)
                    y += (int)((xv >> (8 * jj)) & 0xFFu) * w2r[i * 4 + jj];
            }
        }
        y >>= 6;
        y = y < 0 ? 0 : (y > 127 ? 127 : y);
        const int owx = RAWW ? (int)((const int8_t*)owv)[t] : ((const int*)owv)[t];
        int pr = y * owx;
        #pragma unroll
        for (int off = 16; off > 0; off >>= 1) pr += __shfl_down(pr, off, 32);
        if (t == 0) atomicAdd(ws, pr);
    }
}

__global__ __launch_bounds__(256, 4) void nnue_mono(
    const void* __restrict__ pp, const int* __restrict__ kp,
    const void* __restrict__ W,  const void* __restrict__ ib,
    const void* __restrict__ w1, const int* __restrict__ b1,
    const void* __restrict__ w2, const int* __restrict__ b2,
    const void* __restrict__ ow, int* __restrict__ ws)
{
    __shared__ SharedBuf sh;
    const int raww = ws[1], rawpp = ws[2];
    if (raww) {
        if (rawpp) mono_body<true,  true >(pp, kp, W, ib, w1, b1, w2, b2, ow, ws, sh);
        else       mono_body<true,  false>(pp, kp, W, ib, w1, b1, w2, b2, ow, ws, sh);
    } else {
        if (rawpp) mono_body<false, true >(pp, kp, W, ib, w1, b1, w2, b2, ow, ws, sh);
        else       mono_body<false, false>(pp, kp, W, ib, w1, b1, w2, b2, ow, ws, sh);
    }
}

__global__ void nnue_finalize(const int* __restrict__ ws, const int* __restrict__ ob,
                              int* __restrict__ out) {
    out[0] = (ws[0] + ob[0]) >> 4;  // floor_divide(s, 16)
}

// ============================ host launch ============================
extern "C" void kernel_launch(void* const* d_in, const int* in_sizes, int n_in,
                              void* d_out, int out_size, void* d_ws, size_t ws_size,
                              hipStream_t stream)
{
    const void* pp = d_in[0];
    const int*  kp = (const int*)d_in[1];
    const void* W  = d_in[2];
    const void* ib = d_in[3];
    const void* w1 = d_in[4];
    const int*  b1 = (const int*)d_in[5];
    const void* w2 = d_in[6];
    const int*  b2 = (const int*)d_in[7];
    const void* ow = d_in[8];
    const int*  ob = (const int*)d_in[9];
    int* ws  = (int*)d_ws;
    int* out = (int*)d_out;

    const int B = in_sizes[1] / 2;   // king_positions is (B, 2)
    const int nslots = 2 * B;

    const size_t need4 = ((size_t)OFF_PART + (size_t)4 * nslots * (NDIM / 2)) * 4;
    const size_t need2 = ((size_t)OFF_PART + (size_t)2 * nslots * (NDIM / 2)) * 4;
    int rp = 0;
    if (ws_size >= need4) rp = 4;
    else if (ws_size >= need2) rp = 2;

    if (rp && nslots <= MAXSLOTS && B > 0) {
        // one-time (capture-safe, host-side queries only): cooperative grid size
        static int grid_coop = -2;   // -2 uninit, -1 unsupported, >0 grid size
        if (grid_coop == -2) {
            int dev = 0; hipGetDevice(&dev);
            int coop = 0; hipDeviceGetAttribute(&coop, hipDeviceAttributeCooperativeLaunch, dev);
            int ncu = 0;  hipDeviceGetAttribute(&ncu, hipDeviceAttributeMultiprocessorCount, dev);
            int nb = 0;
            hipError_t oe = hipOccupancyMaxActiveBlocksPerMultiprocessor(&nb, nnue_fused, 256, 0);
            if (coop && oe == hipSuccess && nb > 0 && ncu > 0) {
                int gmax = ((nb * ncu) / 64) * 64;             // multiple of 64 for king mapping
                grid_coop = (gmax >= 64) ? (gmax < GRID_MAIN ? gmax : GRID_MAIN) : -1;
            } else {
                grid_coop = -1;
            }
        }
        int nslots_arg = nslots, B_arg = B, rp_arg = rp;
        if (grid_coop > 0) {
            void* args[] = {(void*)&pp, (void*)&kp, (void*)&W, (void*)&ib,
                            (void*)&w1, (void*)&b1, (void*)&w2, (void*)&b2,
                            (void*)&ow, (void*)&ob, (void*)&ws, (void*)&out,
                            (void*)&nslots_arg, (void*)&B_arg, (void*)&rp_arg};
            hipError_t e = hipLaunchCooperativeKernel(nnue_fused, dim3(grid_coop), dim3(256),
                                                      args, 0, stream);
            if (e == hipSuccess) return;
            grid_coop = -1;  // don't retry the cooperative path
        }
        // non-cooperative fallback: 3 launches (bucket -> gather -> combine+finalize)
        hipLaunchKernelGGL(k_bucket, dim3(64), dim3(256), 0, stream, kp, ws, nslots);
        hipLaunchKernelGGL(k_gather, dim3(GRID_MAIN), dim3(256), 0, stream, pp, W, ws, nslots, rp);
        hipLaunchKernelGGL(k_combine, dim3(GRID_MAIN), dim3(256), 0, stream,
                           kp, pp, W, ib, w1, b1, w2, b2, ow, ob, ws, out, nslots, B, rp);
        return;
    }

    // fallback: monolithic path
    hipLaunchKernelGGL(detect_layout, dim3(1), dim3(1), 0, stream,
                       (const int*)W, (const int*)pp, ws);
    hipLaunchKernelGGL(nnue_mono, dim3(B), dim3(256), 0, stream,
                       pp, kp, W, ib, w1, b1, w2, b2, ow, ws);
    hipLaunchKernelGGL(nnue_finalize, dim3(1), dim3(1), 0, stream, ws, ob, out);
}

// Round 3
// 145.948 us; speedup vs baseline: 1.7999x; 1.7999x over previous
//
#include <hip/hip_runtime.h>
#include <stdint.h>

#define NDIM  256   // accumulator width
#define NFEAT 640   // piece features per sample
#define NROWS 641   // 640 features + 1 king bias row
#define SG    8     // slots processed together per unit
#define KCAP  2048  // per-king slot-list capacity (covers any skew)
#define MAXSLOTS 2048
#define GRID_GATHER 1024
#define GRID_COMBINE 512
#define OFF_KCNT  8                         // ws int offsets
#define OFF_KLIST 128
#define OFF_PART  (OFF_KLIST + 64 * KCAP)   // 131200 ints

typedef unsigned short ushort4v __attribute__((ext_vector_type(4)));

// LDS overlay (per-kernel usage)
struct FusedLds {
    union {
        unsigned mask[4][320];   // gather: per-WAVE row-activity masks (5120 B) -> no barriers
        struct { alignas(16) int8_t x[NDIM]; int fc[256]; alignas(4) int8_t x2[32]; } c;
        int bcnt;                // bucket: per-king LDS compaction counter
    };
};

__device__ __forceinline__ void detect_flags(const void* W, const void* pp,
                                             int* raww, int* rawpp)
{
    int a = 0, b = 0;
    const int* W32 = (const int*)W;
    const int* pp32 = (const int*)pp;
    for (int i = 0; i < 16; ++i) {
        const int v = W32[i];                  // int32 layout => |v| <= 32767
        if (v > 32767 || v < -32768) a = 1;    // packed int16 pairs look huge
        const int u = pp32[i];                 // int32 layout => {0,1}
        if (u != 0 && u != 1) b = 1;           // packed bool bytes exceed 1
    }
    *raww = a; *rawpp = b;
}

// ============================ kernel 1: distributed bucketing ============================
// Block k (k < 64) compacts king k's slot ids into klist[k*KCAP..] (unordered — u16 adds
// commute so group composition/order is irrelevant). Block 0 also zeroes sum/ticket and
// publishes layout flags so later kernels read 2 words instead of 32 serial loads.
__global__ __launch_bounds__(256) void k_bucket(const int* __restrict__ kp,
                                                const void* __restrict__ W,
                                                const void* __restrict__ pp,
                                                int* __restrict__ ws, int nslots)
{
    __shared__ int bcnt;
    const int bid = blockIdx.x, t = threadIdx.x;
    int* kcnt  = ws + OFF_KCNT;
    int* klist = ws + OFF_KLIST;

    if (bid == 0 && t == 0) {
        int raww, rawpp;
        detect_flags(W, pp, &raww, &rawpp);
        ws[0] = 0; ws[1] = raww; ws[2] = rawpp; ws[3] = 0;
    }
    if (t == 0) bcnt = 0;
    __syncthreads();
    for (int s = t; s < nslots; s += 256) {
        if (kp[s] == bid) {
            const int pos = atomicAdd(&bcnt, 1);
            if (pos < KCAP) klist[bid * KCAP + pos] = s;
        }
    }
    __syncthreads();
    if (t == 0) kcnt[bid] = (bcnt > KCAP) ? KCAP : bcnt;
}

// ============================ kernel 2: wave-autonomous gather ============================
// Unit = (king k, row-part p, slot-group gi). Each WAVE owns whole units: builds its own
// row masks in a private LDS strip, accumulates packed-u16 partials in registers (lane l
// holds dims [4l,4l+4)), stores directly to partial[p][slot]. Zero __syncthreads.
template<bool RAWW, bool RAWPP>
__device__ __forceinline__ void gather_phase(
    const void* __restrict__ ppv, const void* __restrict__ Wv,
    const int* __restrict__ kcnt, const int* __restrict__ klist,
    unsigned short* __restrict__ partial, int nslots, int rp,
    unsigned* __restrict__ maskbase)
{
    const int bid = blockIdx.x;
    const int k = bid & 63;                    // bid%8 == k%8 -> XCD pinning for W[k]
    const int t = threadIdx.x, l = t & 63, g = t >> 6;
    const int nwv = (gridDim.x >> 6) << 2;     // waves per king (64 at grid 1024)
    const int wv0 = ((bid >> 6) << 2) + g;
    unsigned* mym = maskbase + g * 320;        // this wave's private mask strip

    const int cnt = kcnt[k];
    if (cnt <= 0) return;
    const int gmax = (cnt + SG - 1) >> 3;
    const int nunits = rp * gmax;              // covers ANY cnt <= KCAP
    const int rpb = NFEAT / rp;                // 160 (rp=4) or 320 (rp=2)
    const int pshift = (rp == 4) ? 2 : 1;
    const char* Wk = (const char*)Wv + (size_t)k * NROWS * NDIM * (RAWW ? 2 : 4);
    const int* kl = klist + k * KCAP;

    for (int u = wv0; u < nunits; u += nwv) {
        const int p = u & (rp - 1);
        const int gi = u >> pshift;
        const int base = gi * SG;
        const int ns = min(SG, cnt - base);
        const int r0 = p * rpb;

        int slots[SG], samps[SG];
        #pragma unroll
        for (int i = 0; i < SG; ++i) {
            const int s = kl[base + (i < ns ? i : ns - 1)];
            slots[i] = s; samps[i] = s >> 1;   // s = 2*sample + side
        }

        // per-wave mask build: lane handles rows r = l, l+64, ...
        for (int r = l; r < rpb; r += 64) {
            unsigned mm = 0;
            #pragma unroll
            for (int i = 0; i < SG; ++i) {
                int v;
                if (RAWPP) v = ((const uint8_t*)ppv)[(size_t)samps[i] * NFEAT + r0 + r];
                else       v = ((const int*)ppv)[(size_t)samps[i] * NFEAT + r0 + r];
                mm |= (v != 0 ? 1u : 0u) << i;
            }
            mym[r] = (ns < SG) ? (mm & ((1u << ns) - 1u)) : mm;
        }
        // wave-local LDS visibility (private strip -> only this wave's writes matter)
        asm volatile("s_waitcnt lgkmcnt(0)" ::: "memory");

        ushort4v acc[SG];
        #pragma unroll
        for (int i = 0; i < SG; ++i) acc[i] = (ushort4v)0;

        // row loop: 4 row loads in flight, scalar-branch masked packed-u16 adds (mod 2^16)
        const char* rb = Wk + (size_t)r0 * (RAWW ? 512 : 1024) + (size_t)l * (RAWW ? 8 : 16);
        const int rstep = RAWW ? 2048 : 4096;
        for (int r = 0; r < rpb; r += 4, rb += rstep) {
            ushort4v w0, w1, w2, w3;
            if constexpr (RAWW) {
                w0 = *(const ushort4v*)(rb);
                w1 = *(const ushort4v*)(rb + 512);
                w2 = *(const ushort4v*)(rb + 1024);
                w3 = *(const ushort4v*)(rb + 1536);
            } else {
                const int4 u0 = *(const int4*)(rb);
                const int4 u1 = *(const int4*)(rb + 1024);
                const int4 u2 = *(const int4*)(rb + 2048);
                const int4 u3 = *(const int4*)(rb + 3072);
                w0.x=(unsigned short)u0.x; w0.y=(unsigned short)u0.y; w0.z=(unsigned short)u0.z; w0.w=(unsigned short)u0.w;
                w1.x=(unsigned short)u1.x; w1.y=(unsigned short)u1.y; w1.z=(unsigned short)u1.z; w1.w=(unsigned short)u1.w;
                w2.x=(unsigned short)u2.x; w2.y=(unsigned short)u2.y; w2.z=(unsigned short)u2.z; w2.w=(unsigned short)u2.w;
                w3.x=(unsigned short)u3.x; w3.y=(unsigned short)u3.y; w3.z=(unsigned short)u3.z; w3.w=(unsigned short)u3.w;
            }
            unsigned m0 = mym[r+0], m1 = mym[r+1], m2 = mym[r+2], m3 = mym[r+3];
            m0 = __builtin_amdgcn_readfirstlane(m0);   // wave-uniform -> scalar branches
            m1 = __builtin_amdgcn_readfirstlane(m1);
            m2 = __builtin_amdgcn_readfirstlane(m2);
            m3 = __builtin_amdgcn_readfirstlane(m3);
            #pragma unroll
            for (int i = 0; i < SG; ++i) {
                if (m0 & (1u << i)) acc[i] += w0;      // 2x v_pk_add_u16 each
                if (m1 & (1u << i)) acc[i] += w1;
                if (m2 & (1u << i)) acc[i] += w2;
                if (m3 & (1u << i)) acc[i] += w3;
            }
        }

        // direct store: lane l writes dims [4l,4l+4) -> 512 B/wave coalesced
        #pragma unroll
        for (int i = 0; i < SG; ++i)
            if (i < ns)
                *(ushort4v*)&partial[((size_t)p * nslots + slots[i]) * NDIM + (size_t)l * 4] = acc[i];
    }
}

__global__ __launch_bounds__(256, 4) void k_gather(
    const void* __restrict__ pp, const void* __restrict__ W,
    int* __restrict__ ws, int nslots, int rp)
{
    __shared__ FusedLds sh;
    const int raww = ws[1], rawpp = ws[2];     // published by k_bucket
    int* kcnt  = ws + OFF_KCNT;
    int* klist = ws + OFF_KLIST;
    unsigned short* partial = (unsigned short*)(ws + OFF_PART);
    if (raww) {
        if (rawpp) gather_phase<true,  true >(pp, W, kcnt, klist, partial, nslots, rp, &sh.mask[0][0]);
        else       gather_phase<true,  false>(pp, W, kcnt, klist, partial, nslots, rp, &sh.mask[0][0]);
    } else {
        if (rawpp) gather_phase<false, true >(pp, W, kcnt, klist, partial, nslots, rp, &sh.mask[0][0]);
        else       gather_phase<false, false>(pp, W, kcnt, klist, partial, nslots, rp, &sh.mask[0][0]);
    }
}

// ============================ kernel 3: combine + FC + ticket finalize ============================
template<bool RAWW>
__device__ __forceinline__ void combine_phase(
    const unsigned short* __restrict__ partial, const int* __restrict__ kp,
    const void* __restrict__ Wv, const void* __restrict__ ibv,
    const void* __restrict__ w1v, const int* __restrict__ b1,
    const void* __restrict__ w2v, const int* __restrict__ b2,
    const void* __restrict__ owv, const int* __restrict__ ob,
    int* __restrict__ ws, int* __restrict__ out,
    int nslots, int B, int rp, FusedLds& sh)
{
    const int t = threadIdx.x;
    int blocksum = 0;

    for (int b = blockIdx.x; b < B; b += gridDim.x) {
        const int k0 = kp[2 * b + 0];
        const int k1 = kp[2 * b + 1];
        {
            unsigned tot = 0;  // u16 arithmetic carried in u32; truncate at end
            for (int pi = 0; pi < rp; ++pi) {
                tot += partial[((size_t)pi * nslots + 2 * b + 0) * NDIM + t];
                tot += partial[((size_t)pi * nslots + 2 * b + 1) * NDIM + t];
            }
            if (RAWW) {
                const uint16_t* Wq = (const uint16_t*)Wv;
                tot += Wq[((size_t)k0 * NROWS + NFEAT) * NDIM + t];
                tot += Wq[((size_t)k1 * NROWS + NFEAT) * NDIM + t];
                tot += ((const uint16_t*)ibv)[t];
            } else {
                const int* Wq = (const int*)Wv;
                tot += (unsigned)Wq[((size_t)k0 * NROWS + NFEAT) * NDIM + t];
                tot += (unsigned)Wq[((size_t)k1 * NROWS + NFEAT) * NDIM + t];
                tot += (unsigned)((const int*)ibv)[t];
            }
            int v = (int)(int16_t)(uint16_t)tot;   // int16 wraparound semantics
            v = v < 0 ? 0 : (v > 127 ? 127 : v);
            sh.c.x[t] = (int8_t)v;
        }
        __syncthreads();

        // ---- FC1: 32 outputs over concat([x,x]) = fold the two 256-halves of w1 ----
        {
            const int o = t >> 3, part = t & 7;
            int y = 0;
            const uint32_t* xw = (const uint32_t*)sh.c.x;
            if (RAWW) {
                const uint32_t* w1r = (const uint32_t*)((const char*)w1v + o * 512);
                #pragma unroll
                for (int i = 0; i < 8; ++i) {
                    const int wi = part * 8 + i;
                    const uint32_t xv = xw[wi];
                    const uint32_t wa = w1r[wi];
                    const uint32_t wb = w1r[64 + wi];
                    #pragma unroll
                    for (int jj = 0; jj < 4; ++jj) {
                        const int xj  = (int)((xv >> (8 * jj)) & 0xFFu);
                        const int waj = (int)(int8_t)(uint8_t)(wa >> (8 * jj));
                        const int wbj = (int)(int8_t)(uint8_t)(wb >> (8 * jj));
                        y += xj * (waj + wbj);
                    }
                }
            } else {
                const int* w1r = (const int*)w1v + o * 512;
                #pragma unroll
                for (int i = 0; i < 8; ++i) {
                    const int wi = part * 8 + i;
                    const uint32_t xv = xw[wi];
                    #pragma unroll
                    for (int jj = 0; jj < 4; ++jj) {
                        const int xj = (int)((xv >> (8 * jj)) & 0xFFu);
                        y += xj * (w1r[wi * 4 + jj] + w1r[256 + wi * 4 + jj]);
                    }
                }
            }
            sh.c.fc[t] = y;
        }
        __syncthreads();

        if (t < 32) {
            int y = b1[t];
            #pragma unroll
            for (int pq = 0; pq < 8; ++pq) y += sh.c.fc[t * 8 + pq];
            y >>= 6;                                  // floor_divide(y, 64)
            y = y < 0 ? 0 : (y > 127 ? 127 : y);
            sh.c.x2[t] = (int8_t)y;
        }
        __syncthreads();

        // ---- FC2 + output dot ----
        if (t < 32) {
            int y = b2[t];
            const uint32_t* x2w = (const uint32_t*)sh.c.x2;
            if (RAWW) {
                const uint32_t* w2r = (const uint32_t*)((const char*)w2v + t * 32);
                #pragma unroll
                for (int i = 0; i < 8; ++i) {
                    const uint32_t xv = x2w[i];
                    const uint32_t wv = w2r[i];
                    #pragma unroll
                    for (int jj = 0; jj < 4; ++jj)
                        y += (int)((xv >> (8 * jj)) & 0xFFu) * (int)(int8_t)(uint8_t)(wv >> (8 * jj));
                }
            } else {
                const int* w2r = (const int*)w2v + t * 32;
                #pragma unroll
                for (int i = 0; i < 8; ++i) {
                    const uint32_t xv = x2w[i];
                    #pragma unroll
                    for (int jj = 0; jj < 4; ++jj)
                        y += (int)((xv >> (8 * jj)) & 0xFFu) * w2r[i * 4 + jj];
                }
            }
            y >>= 6;
            y = y < 0 ? 0 : (y > 127 ? 127 : y);
            const int owx = RAWW ? (int)((const int8_t*)owv)[t] : ((const int*)owv)[t];
            int pr = y * owx;
            #pragma unroll
            for (int off = 16; off > 0; off >>= 1) pr += __shfl_down(pr, off, 32);
            if (t == 0) blocksum += pr;
        }
        __syncthreads();   // sh.c reused next sample
    }

    // one atomic per participating block; last ticket writes the output
    const int nticket = (int)gridDim.x < B ? (int)gridDim.x : B;
    if (t == 0 && (int)blockIdx.x < nticket) {
        atomicAdd(&ws[0], blocksum);
        __threadfence();                               // order add before ticket (device scope)
        const int ticket = atomicAdd(&ws[3], 1);
        if (ticket == nticket - 1) {
            const int s = atomicAdd(&ws[0], 0);        // device-scope read
            out[0] = (s + ob[0]) >> 4;                 // floor_divide(s, 16)
        }
    }
}

__global__ __launch_bounds__(256) void k_combine(
    const int* __restrict__ kp, const void* __restrict__ W,
    const void* __restrict__ ib,
    const void* __restrict__ w1, const int* __restrict__ b1,
    const void* __restrict__ w2, const int* __restrict__ b2,
    const void* __restrict__ ow, const int* __restrict__ ob,
    int* __restrict__ ws, int* __restrict__ out, int nslots, int B, int rp)
{
    __shared__ FusedLds sh;
    unsigned short* partial = (unsigned short*)(ws + OFF_PART);
    if (ws[1]) combine_phase<true >(partial, kp, W, ib, w1, b1, w2, b2, ow, ob, ws, out, nslots, B, rp, sh);
    else       combine_phase<false>(partial, kp, W, ib, w1, b1, w2, b2, ow, ob, ws, out, nslots, B, rp, sh);
}

// ============================ mono fallback (tiny ws / huge batch) ============================
struct SharedBuf {
    uint8_t pp[NFEAT];
    int     acc[4][NDIM];
    alignas(16) int8_t x[NDIM];
    int     fc[256];
    alignas(4) int8_t x2[32];
    int     list[4][160];
};

__global__ void detect_layout(const int* __restrict__ W32, const int* __restrict__ pp32,
                              int* __restrict__ ws) {
    int raww, rawpp;
    detect_flags(W32, pp32, &raww, &rawpp);
    ws[0] = 0; ws[1] = raww; ws[2] = rawpp;
}

template<bool RAWW, bool RAWPP>
__device__ __forceinline__ void mono_body(
    const void* __restrict__ ppv, const int* __restrict__ kp,
    const void* __restrict__ Wv,  const void* __restrict__ ibv,
    const void* __restrict__ w1v, const int* __restrict__ b1,
    const void* __restrict__ w2v, const int* __restrict__ b2,
    const void* __restrict__ owv, int* __restrict__ ws, SharedBuf& sh)
{
    const int b = blockIdx.x;
    const int t = threadIdx.x;
    const int l = t & 63;
    const int g = t >> 6;

    if (RAWPP) {
        const uint32_t* src = (const uint32_t*)((const uint8_t*)ppv + (size_t)b * NFEAT);
        if (t < NFEAT / 4) ((uint32_t*)sh.pp)[t] = src[t];
    } else {
        const int* src = (const int*)ppv + (size_t)b * NFEAT;
        for (int i = t; i < NFEAT; i += 256) sh.pp[i] = (uint8_t)(src[i] != 0);
    }
    __syncthreads();

    const int base = g * 160;
    int cnt = 0;
    for (int c = 0; c < 160; c += 64) {
        const int idx = c + l;
        const bool flag = (idx < 160) && (sh.pp[base + idx] != 0);
        const unsigned long long mmask = __ballot(flag);
        const int pos = cnt + (int)__popcll(mmask & ((1ull << l) - 1ull));
        if (flag) sh.list[g][pos] = base + idx;
        cnt += (int)__popcll(mmask);
    }

    const int k0 = kp[b * 2 + 0];
    const int k1 = kp[b * 2 + 1];
    int a0 = 0, a1 = 0, a2 = 0, a3 = 0, a4 = 0, a5 = 0, a6 = 0, a7 = 0;

    if (RAWW) {
        const char* W0 = (const char*)Wv + (size_t)k0 * (NROWS * NDIM * 2);
        const char* W1 = (const char*)Wv + (size_t)k1 * (NROWS * NDIM * 2);
        const int lo = l * 8;
        auto step = [&](int f) {
            const uint2 u0 = *(const uint2*)(W0 + f * 512 + lo);
            const uint2 u1 = *(const uint2*)(W1 + f * 512 + lo);
            a0 += (int)(u0.x & 0xFFFFu); a1 += (int)(u0.x >> 16);
            a2 += (int)(u0.y & 0xFFFFu); a3 += (int)(u0.y >> 16);
            a4 += (int)(u1.x & 0xFFFFu); a5 += (int)(u1.x >> 16);
            a6 += (int)(u1.y & 0xFFFFu); a7 += (int)(u1.y >> 16);
        };
        int j = 0;
        for (; j + 4 <= cnt; j += 4) {
            const int f0 = sh.list[g][j], f1 = sh.list[g][j + 1];
            const int f2 = sh.list[g][j + 2], f3 = sh.list[g][j + 3];
            step(f0); step(f1); step(f2); step(f3);
        }
        for (; j < cnt; ++j) step(sh.list[g][j]);
    } else {
        const char* W0 = (const char*)Wv + (size_t)k0 * (NROWS * NDIM * 4);
        const char* W1 = (const char*)Wv + (size_t)k1 * (NROWS * NDIM * 4);
        const int lo = l * 16;
        auto step = [&](int f) {
            const int4 u0 = *(const int4*)(W0 + f * 1024 + lo);
            const int4 u1 = *(const int4*)(W1 + f * 1024 + lo);
            a0 += u0.x; a1 += u0.y; a2 += u0.z; a3 += u0.w;
            a4 += u1.x; a5 += u1.y; a6 += u1.z; a7 += u1.w;
        };
        int j = 0;
        for (; j + 4 <= cnt; j += 4) {
            const int f0 = sh.list[g][j], f1 = sh.list[g][j + 1];
            const int f2 = sh.list[g][j + 2], f3 = sh.list[g][j + 3];
            step(f0); step(f1); step(f2); step(f3);
        }
        for (; j < cnt; ++j) step(sh.list[g][j]);
    }

    sh.acc[g][4 * l + 0] = a0 + a4;
    sh.acc[g][4 * l + 1] = a1 + a5;
    sh.acc[g][4 * l + 2] = a2 + a6;
    sh.acc[g][4 * l + 3] = a3 + a7;
    __syncthreads();

    {
        const int d = t;
        int tot = sh.acc[0][d] + sh.acc[1][d] + sh.acc[2][d] + sh.acc[3][d];
        int kb0, kb1, ibx;
        if (RAWW) {
            const int16_t* Wq = (const int16_t*)Wv;
            kb0 = Wq[((size_t)k0 * NROWS + NFEAT) * NDIM + d];
            kb1 = Wq[((size_t)k1 * NROWS + NFEAT) * NDIM + d];
            ibx = ((const int16_t*)ibv)[d];
        } else {
            const int* Wq = (const int*)Wv;
            kb0 = Wq[((size_t)k0 * NROWS + NFEAT) * NDIM + d];
            kb1 = Wq[((size_t)k1 * NROWS + NFEAT) * NDIM + d];
            ibx = ((const int*)ibv)[d];
        }
        tot += kb0 + kb1 + ibx;
        int v = (int)(int16_t)(uint16_t)(uint32_t)tot;
        v = v < 0 ? 0 : (v > 127 ? 127 : v);
        sh.x[d] = (int8_t)v;
    }
    __syncthreads();

    {
        const int o = t >> 3, part = t & 7;
        int y = 0;
        const uint32_t* xw = (const uint32_t*)sh.x;
        if (RAWW) {
            const uint32_t* w1r = (const uint32_t*)((const char*)w1v + o * 512);
            #pragma unroll
            for (int i = 0; i < 8; ++i) {
                const int wi = part * 8 + i;
                const uint32_t xv = xw[wi];
                const uint32_t wa = w1r[wi];
                const uint32_t wb = w1r[64 + wi];
                #pragma unroll
                for (int jj = 0; jj < 4; ++jj) {
                    const int xj  = (int)((xv >> (8 * jj)) & 0xFFu);
                    const int waj = (int)(int8_t)(uint8_t)(wa >> (8 * jj));
                    const int wbj = (int)(int8_t)(uint8_t)(wb >> (8 * jj));
                    y += xj * (waj + wbj);
                }
            }
        } else {
            const int* w1r = (const int*)w1v + o * 512;
            #pragma unroll
            for (int i = 0; i < 8; ++i) {
                const int wi = part * 8 + i;
                const uint32_t xv = xw[wi];
                #pragma unroll
                for (int jj = 0; jj < 4; ++jj) {
                    const int xj = (int)((xv >> (8 * jj)) & 0xFFu);
                    y += xj * (w1r[wi * 4 + jj] + w1r[256 + wi * 4 + jj]);
                }
            }
        }
        sh.fc[t] = y;
    }
    __syncthreads();

    if (t < 32) {
        int y = b1[t];
        #pragma unroll
        for (int pq = 0; pq < 8; ++pq) y += sh.fc[t * 8 + pq];
        y >>= 6;
        y = y < 0 ? 0 : (y > 127 ? 127 : y);
        sh.x2[t] = (int8_t)y;
    }
    __syncthreads();

    if (t < 32) {
        int y = b2[t];
        const uint32_t* x2w = (const uint32_t*)sh.x2;
        if (RAWW) {
            const uint32_t* w2r = (const uint32_t*)((const char*)w2v + t * 32);
            #pragma unroll
            for (int i = 0; i < 8; ++i) {
                const uint32_t xv = x2w[i];
                const uint32_t wv = w2r[i];
                #pragma unroll
                for (int jj = 0; jj < 4; ++jj)
                    y += (int)((xv >> (8 * jj)) & 0xFFu) * (int)(int8_t)(uint8_t)(wv >> (8 * jj));
            }
        } else {
            const int* w2r = (const int*)w2v + t * 32;
            #pragma unroll
            for (int i = 0; i < 8; ++i) {
                const uint32_t xv = x2w[i];
                #pragma unroll
                for (int jj = 0; jj < 4; ++jj)
                    y += (int)((xv >> (8 * jj)) & 0xFFu) * w2r[i * 4 + jj];
            }
        }
        y >>= 6;
        y = y < 0 ? 0 : (y > 127 ? 127 : y);
        const int owx = RAWW ? (int)((const int8_t*)owv)[t] : ((const int*)owv)[t];
        int pr = y * owx;
        #pragma unroll
        for (int off = 16; off > 0; off >>= 1) pr += __shfl_down(pr, off, 32);
        if (t == 0) atomicAdd(ws, pr);
    }
}

__global__ __launch_bounds__(256, 4) void nnue_mono(
    const void* __restrict__ pp, const int* __restrict__ kp,
    const void* __restrict__ W,  const void* __restrict__ ib,
    const void* __restrict__ w1, const int* __restrict__ b1,
    const void* __restrict__ w2, const int* __restrict__ b2,
    const void* __restrict__ ow, int* __restrict__ ws)
{
    __shared__ SharedBuf sh;
    const int raww = ws[1], rawpp = ws[2];
    if (raww) {
        if (rawpp) mono_body<true,  true >(pp, kp, W, ib, w1, b1, w2, b2, ow, ws, sh);
        else       mono_body<true,  false>(pp, kp, W, ib, w1, b1, w2, b2, ow, ws, sh);
    } else {
        if (rawpp) mono_body<false, true >(pp, kp, W, ib, w1, b1, w2, b2, ow, ws, sh);
        else       mono_body<false, false>(pp, kp, W, ib, w1, b1, w2, b2, ow, ws, sh);
    }
}

__global__ void nnue_finalize(const int* __restrict__ ws, const int* __restrict__ ob,
                              int* __restrict__ out) {
    out[0] = (ws[0] + ob[0]) >> 4;  // floor_divide(s, 16)
}

// ============================ host launch ============================
extern "C" void kernel_launch(void* const* d_in, const int* in_sizes, int n_in,
                              void* d_out, int out_size, void* d_ws, size_t ws_size,
                              hipStream_t stream)
{
    const void* pp = d_in[0];
    const int*  kp = (const int*)d_in[1];
    const void* W  = d_in[2];
    const void* ib = d_in[3];
    const void* w1 = d_in[4];
    const int*  b1 = (const int*)d_in[5];
    const void* w2 = d_in[6];
    const int*  b2 = (const int*)d_in[7];
    const void* ow = d_in[8];
    const int*  ob = (const int*)d_in[9];
    int* ws  = (int*)d_ws;
    int* out = (int*)d_out;

    const int B = in_sizes[1] / 2;   // king_positions is (B, 2)
    const int nslots = 2 * B;

    const size_t need4 = ((size_t)OFF_PART + (size_t)4 * nslots * (NDIM / 2)) * 4;
    const size_t need2 = ((size_t)OFF_PART + (size_t)2 * nslots * (NDIM / 2)) * 4;
    int rp = 0;
    if (ws_size >= need4) rp = 4;
    else if (ws_size >= need2) rp = 2;

    if (rp && nslots <= MAXSLOTS && B > 0) {
        // 3 plain launches — NO cooperative grid.sync (measured ~100 us/sync on gfx950)
        hipLaunchKernelGGL(k_bucket, dim3(64), dim3(256), 0, stream,
                           kp, W, pp, ws, nslots);
        hipLaunchKernelGGL(k_gather, dim3(GRID_GATHER), dim3(256), 0, stream,
                           pp, W, ws, nslots, rp);
        hipLaunchKernelGGL(k_combine, dim3(GRID_COMBINE), dim3(256), 0, stream,
                           kp, W, ib, w1, b1, w2, b2, ow, ob, ws, out, nslots, B, rp);
        return;
    }

    // fallback: monolithic path
    hipLaunchKernelGGL(detect_layout, dim3(1), dim3(1), 0, stream,
                       (const int*)W, (const int*)pp, ws);
    hipLaunchKernelGGL(nnue_mono, dim3(B), dim3(256), 0, stream,
                       pp, kp, W, ib, w1, b1, w2, b2, ow, ws);
    hipLaunchKernelGGL(nnue_finalize, dim3(1), dim3(1), 0, stream, ws, ob, out);
}